// Round 1
// baseline (1393.842 us; speedup 1.0000x reference)
//
#include <hip/hip_runtime.h>

#define N_NODES 50000
#define N_PAD   50016      // padded to /32 for unguarded matmul tiles
#define N_EDGES 1600000
#define N_GRAPHS 256
#define F_IN 1080
#define HID 128

// ---------------------------------------------------------------------------
// Effective 64-tap filter of three composed (k=10, s=2) convs with shared w:
// y3[f] = sum_t eff[t] * x[8f + t],  eff[t] = sum_{a+2b+4c==t} w[a] w[b] w[c]
// bias composes to b_eff = b*(s^2 + s + 1), s = sum(w).
// ---------------------------------------------------------------------------
__global__ void eff_kernel(const float* __restrict__ w, const float* __restrict__ b,
                           float* __restrict__ eff) {
  int t = threadIdx.x;  // 0..63
  float acc = 0.f;
  for (int a = 0; a < 10; ++a)
    for (int bb = 0; bb < 10; ++bb) {
      int r = t - a - 2 * bb;
      if (r >= 0 && (r & 3) == 0 && (r >> 2) < 10)
        acc += w[a] * w[bb] * w[r >> 2];
    }
  eff[t] = acc;
  if (t == 0) {
    float s = 0.f;
    for (int i = 0; i < 10; ++i) s += w[i];
    eff[64] = b[0] * (s * s + s + 1.f);
  }
}

// One node per 128 threads; thread f does 16 aligned float4 loads (window 8f..8f+63).
__global__ __launch_bounds__(256) void conv_kernel(const float* __restrict__ x,
                                                   const float* __restrict__ eff,
                                                   float* __restrict__ h) {
  int node = blockIdx.x * 2 + (threadIdx.x >> 7);
  int f = threadIdx.x & 127;
  const float* xr = x + (size_t)node * F_IN + 8 * f;   // 32B-aligned (row is 4320B, /16)
  float acc = eff[64];
  #pragma unroll
  for (int t4 = 0; t4 < 16; ++t4) {
    float4 v = *reinterpret_cast<const float4*>(xr + 4 * t4);
    acc = fmaf(eff[4 * t4 + 0], v.x, acc);
    acc = fmaf(eff[4 * t4 + 1], v.y, acc);
    acc = fmaf(eff[4 * t4 + 2], v.z, acc);
    acc = fmaf(eff[4 * t4 + 3], v.w, acc);
  }
  h[(size_t)node * HID + f] = acc;
}

// ---------------------------------------------------------------------------
// CSR-by-dst build
// ---------------------------------------------------------------------------
__global__ void deg_kernel(const int* __restrict__ ei, int* __restrict__ deg) {
  int e = blockIdx.x * 256 + threadIdx.x;
  if (e < N_EDGES) atomicAdd(&deg[ei[N_EDGES + e]], 1);
}

// Single-block exclusive scan (N=50000, 1024 threads, Hillis-Steele per chunk).
__global__ void scan_kernel(const int* __restrict__ deg, int* __restrict__ row_ptr, int n) {
  __shared__ int s[1024];
  __shared__ int carry_s;
  int tid = threadIdx.x;
  if (tid == 0) carry_s = 0;
  __syncthreads();
  for (int base = 0; base < n; base += 1024) {
    int i = base + tid;
    int v = (i < n) ? deg[i] : 0;
    s[tid] = v;
    __syncthreads();
    int val = v;
    for (int off = 1; off < 1024; off <<= 1) {
      int add = (tid >= off) ? s[tid - off] : 0;
      __syncthreads();
      val += add;
      s[tid] = val;
      __syncthreads();
    }
    int carry = carry_s;
    if (i < n) row_ptr[i] = carry + val - v;  // exclusive
    __syncthreads();
    if (tid == 1023) carry_s = carry + val;   // chunk total
    __syncthreads();
  }
  if (tid == 0) row_ptr[n] = carry_s;
}

__global__ void dinv_kernel(const int* __restrict__ deg, float* __restrict__ dinv) {
  int i = blockIdx.x * 256 + threadIdx.x;
  if (i < N_NODES) dinv[i] = rsqrtf((float)(deg[i] + 1));  // +1 self-loop, deg>=1
}

__global__ void fill_kernel(const int* __restrict__ ei, const int* __restrict__ row_ptr,
                            int* __restrict__ fillc, const float* __restrict__ dinv,
                            int2* __restrict__ csr) {
  int e = blockIdx.x * 256 + threadIdx.x;
  if (e >= N_EDGES) return;
  int sN = ei[e], d = ei[N_EDGES + e];
  int p = atomicAdd(&fillc[d], 1);
  csr[row_ptr[d] + p] = make_int2(sN, __float_as_int(dinv[sN] * dinv[d]));
}

// ---------------------------------------------------------------------------
// f32 matmul: out[N_PAD,128] = h[N_PAD,128] @ W[128,128]
// block: 256 thr = 8 node-groups x 32 col-groups; thread: 4 nodes x 4 cols
// ---------------------------------------------------------------------------
__global__ __launch_bounds__(256) void matmul_kernel(const float* __restrict__ h,
                                                     const float* __restrict__ W,
                                                     float* __restrict__ out) {
  int t = threadIdx.x;
  int c0 = (t & 31) << 2;
  int n0 = blockIdx.x * 32 + ((t >> 5) << 2);
  float acc[4][4];
  #pragma unroll
  for (int i = 0; i < 4; ++i)
    #pragma unroll
    for (int j = 0; j < 4; ++j) acc[i][j] = 0.f;
  for (int k = 0; k < HID; k += 4) {
    float4 w0 = *(const float4*)(W + (k + 0) * HID + c0);
    float4 w1 = *(const float4*)(W + (k + 1) * HID + c0);
    float4 w2 = *(const float4*)(W + (k + 2) * HID + c0);
    float4 w3 = *(const float4*)(W + (k + 3) * HID + c0);
    #pragma unroll
    for (int i = 0; i < 4; ++i) {
      float4 hv = *(const float4*)(h + (size_t)(n0 + i) * HID + k);
      acc[i][0] = fmaf(hv.x, w0.x, acc[i][0]); acc[i][0] = fmaf(hv.y, w1.x, acc[i][0]);
      acc[i][0] = fmaf(hv.z, w2.x, acc[i][0]); acc[i][0] = fmaf(hv.w, w3.x, acc[i][0]);
      acc[i][1] = fmaf(hv.x, w0.y, acc[i][1]); acc[i][1] = fmaf(hv.y, w1.y, acc[i][1]);
      acc[i][1] = fmaf(hv.z, w2.y, acc[i][1]); acc[i][1] = fmaf(hv.w, w3.y, acc[i][1]);
      acc[i][2] = fmaf(hv.x, w0.z, acc[i][2]); acc[i][2] = fmaf(hv.y, w1.z, acc[i][2]);
      acc[i][2] = fmaf(hv.z, w2.z, acc[i][2]); acc[i][2] = fmaf(hv.w, w3.z, acc[i][2]);
      acc[i][3] = fmaf(hv.x, w0.w, acc[i][3]); acc[i][3] = fmaf(hv.y, w1.w, acc[i][3]);
      acc[i][3] = fmaf(hv.z, w2.w, acc[i][3]); acc[i][3] = fmaf(hv.w, w3.w, acc[i][3]);
    }
  }
  #pragma unroll
  for (int i = 0; i < 4; ++i) {
    float4 r;
    r.x = acc[i][0]; r.y = acc[i][1]; r.z = acc[i][2]; r.w = acc[i][3];
    *(float4*)(out + (size_t)(n0 + i) * HID + c0) = r;
  }
}

// ---------------------------------------------------------------------------
// Aggregate: one wave per node; lane holds channels [2l, 2l+1].
// out[v] = bias + dinv[v]^2 * hW[v] + sum_{e in CSR[v]} norm_e * hW[src_e]
// ---------------------------------------------------------------------------
__global__ __launch_bounds__(256) void aggregate_kernel(
    const float* __restrict__ hW, const int2* __restrict__ csr,
    const int* __restrict__ row_ptr, const float* __restrict__ dinv,
    const float* __restrict__ bias, float* __restrict__ out, int relu) {
  int v = blockIdx.x * 4 + (threadIdx.x >> 6);
  if (v >= N_NODES) return;
  int lane = threadIdx.x & 63;
  float dv = dinv[v];
  float2 hs = ((const float2*)(hW + (size_t)v * HID))[lane];
  float ax = dv * dv * hs.x, ay = dv * dv * hs.y;
  int beg = row_ptr[v], end = row_ptr[v + 1];
  for (int e = beg; e < end; ++e) {
    int2 ev = csr[e];
    float nv = __int_as_float(ev.y);
    float2 hv = ((const float2*)(hW + (size_t)ev.x * HID))[lane];
    ax = fmaf(nv, hv.x, ax);
    ay = fmaf(nv, hv.y, ay);
  }
  float2 b2 = ((const float2*)bias)[lane];
  ax += b2.x; ay += b2.y;
  if (relu) { ax = fmaxf(ax, 0.f); ay = fmaxf(ay, 0.f); }
  ((float2*)(out + (size_t)v * HID))[lane] = make_float2(ax, ay);
}

// ---------------------------------------------------------------------------
// Global mean pool (atomics) + tiny MLP head
// ---------------------------------------------------------------------------
__global__ void pool_kernel(const float* __restrict__ h, const int* __restrict__ batch,
                            float* __restrict__ pooled, float* __restrict__ cnt) {
  int idx = blockIdx.x * 256 + threadIdx.x;
  int node = idx >> 7, c = idx & 127;
  if (node >= N_NODES) return;
  int g = batch[node];
  atomicAdd(&pooled[g * HID + c], h[(size_t)node * HID + c]);
  if (c == 0) atomicAdd(&cnt[g], 1.f);
}

__global__ void mlp_kernel(const float* __restrict__ pooled, const float* __restrict__ cnt,
                           const float* __restrict__ l1w, const float* __restrict__ l1b,
                           const float* __restrict__ l2w, const float* __restrict__ l2b,
                           float* __restrict__ out) {
  int g = blockIdx.x, j = threadIdx.x;  // 64 threads
  float inv = 1.f / fmaxf(cnt[g], 1.f);
  float acc = l1b[j];
  #pragma unroll 8
  for (int k = 0; k < HID; ++k)
    acc = fmaf(pooled[g * HID + k] * inv, l1w[k * 64 + j], acc);
  float p = fmaxf(acc, 0.f) * l2w[j];
  #pragma unroll
  for (int off = 32; off > 0; off >>= 1) p += __shfl_down(p, off, 64);
  if (j == 0) out[g] = 1.f / (1.f + __expf(-(p + l2b[0])));
}

// ---------------------------------------------------------------------------
extern "C" void kernel_launch(void* const* d_in, const int* in_sizes, int n_in,
                              void* d_out, int out_size, void* d_ws, size_t ws_size,
                              hipStream_t stream) {
  const float* x      = (const float*)d_in[0];
  const int*   ei     = (const int*)d_in[1];
  const int*   batch  = (const int*)d_in[2];
  const float* conv_w = (const float*)d_in[3];
  const float* conv_b = (const float*)d_in[4];
  const float* W1 = (const float*)d_in[5];
  const float* b1 = (const float*)d_in[6];
  const float* W2 = (const float*)d_in[7];
  const float* b2 = (const float*)d_in[8];
  const float* W3 = (const float*)d_in[9];
  const float* b3 = (const float*)d_in[10];
  const float* l1w = (const float*)d_in[11];
  const float* l1b = (const float*)d_in[12];
  const float* l2w = (const float*)d_in[13];
  const float* l2b = (const float*)d_in[14];
  float* out = (float*)d_out;

  char* ws = (char*)d_ws;
  size_t off = 0;
  auto alloc = [&](size_t bytes) {
    void* p = ws + off;
    off = (off + bytes + 255) & ~(size_t)255;
    return p;
  };
  float* hA      = (float*)alloc((size_t)N_PAD * HID * 4);
  float* hB      = (float*)alloc((size_t)N_PAD * HID * 4);
  int*   deg     = (int*)alloc((size_t)N_NODES * 4);
  int*   row_ptr = (int*)alloc((size_t)(N_NODES + 1) * 4);
  int*   fillc   = (int*)alloc((size_t)N_NODES * 4);
  float* dinv    = (float*)alloc((size_t)N_NODES * 4);
  int2*  csr     = (int2*)alloc((size_t)N_EDGES * 8);
  float* eff     = (float*)alloc(128 * 4);
  float* pooled  = (float*)alloc((size_t)N_GRAPHS * HID * 4);
  float* cnt     = (float*)alloc((size_t)N_GRAPHS * 4);

  hipMemsetAsync(deg, 0, (size_t)N_NODES * 4, stream);
  hipMemsetAsync(fillc, 0, (size_t)N_NODES * 4, stream);
  hipMemsetAsync(pooled, 0, (size_t)N_GRAPHS * HID * 4, stream);
  hipMemsetAsync(cnt, 0, (size_t)N_GRAPHS * 4, stream);

  eff_kernel<<<1, 64, 0, stream>>>(conv_w, conv_b, eff);
  conv_kernel<<<N_NODES / 2, 256, 0, stream>>>(x, eff, hA);

  deg_kernel<<<(N_EDGES + 255) / 256, 256, 0, stream>>>(ei, deg);
  scan_kernel<<<1, 1024, 0, stream>>>(deg, row_ptr, N_NODES);
  dinv_kernel<<<(N_NODES + 255) / 256, 256, 0, stream>>>(deg, dinv);
  fill_kernel<<<(N_EDGES + 255) / 256, 256, 0, stream>>>(ei, row_ptr, fillc, dinv, csr);

  // layer 1
  matmul_kernel<<<N_PAD / 32, 256, 0, stream>>>(hA, W1, hB);
  aggregate_kernel<<<N_NODES / 4, 256, 0, stream>>>(hB, csr, row_ptr, dinv, b1, hA, 1);
  // layer 2
  matmul_kernel<<<N_PAD / 32, 256, 0, stream>>>(hA, W2, hB);
  aggregate_kernel<<<N_NODES / 4, 256, 0, stream>>>(hB, csr, row_ptr, dinv, b2, hA, 1);
  // layer 3
  matmul_kernel<<<N_PAD / 32, 256, 0, stream>>>(hA, W3, hB);
  aggregate_kernel<<<N_NODES / 4, 256, 0, stream>>>(hB, csr, row_ptr, dinv, b3, hA, 0);

  pool_kernel<<<(N_NODES * HID) / 256, 256, 0, stream>>>(hA, batch, pooled, cnt);
  mlp_kernel<<<N_GRAPHS, 64, 0, stream>>>(pooled, cnt, l1w, l1b, l2w, l2b, out);
}

// Round 2
// 1062.615 us; speedup vs baseline: 1.3117x; 1.3117x over previous
//
#include <hip/hip_runtime.h>

#define N_NODES 50000
#define N_PAD   50016      // padded to /32 for unguarded matmul tiles
#define N_EDGES 1600000
#define N_GRAPHS 256
#define F_IN 1080
#define HID 128

// ---------------------------------------------------------------------------
// Effective 64-tap filter of three composed (k=10, s=2) convs with shared w:
// y3[f] = sum_t eff[t] * x[8f + t],  eff[t] = sum_{a+2b+4c==t} w[a] w[b] w[c]
// bias composes to b_eff = b*(s^2 + s + 1), s = sum(w).
// ---------------------------------------------------------------------------
__global__ void eff_kernel(const float* __restrict__ w, const float* __restrict__ b,
                           float* __restrict__ eff) {
  int t = threadIdx.x;  // 0..63
  float acc = 0.f;
  for (int a = 0; a < 10; ++a)
    for (int bb = 0; bb < 10; ++bb) {
      int r = t - a - 2 * bb;
      if (r >= 0 && (r & 3) == 0 && (r >> 2) < 10)
        acc += w[a] * w[bb] * w[r >> 2];
    }
  eff[t] = acc;
  if (t == 0) {
    float s = 0.f;
    for (int i = 0; i < 10; ++i) s += w[i];
    eff[64] = b[0] * (s * s + s + 1.f);
  }
}

// One node per 128 threads; thread f does 16 aligned float4 loads (window 8f..8f+63).
__global__ __launch_bounds__(256) void conv_kernel(const float* __restrict__ x,
                                                   const float* __restrict__ eff,
                                                   float* __restrict__ h) {
  int node = blockIdx.x * 2 + (threadIdx.x >> 7);
  int f = threadIdx.x & 127;
  const float* xr = x + (size_t)node * F_IN + 8 * f;   // 32B-aligned (row is 4320B, /16)
  float acc = eff[64];
  #pragma unroll
  for (int t4 = 0; t4 < 16; ++t4) {
    float4 v = *reinterpret_cast<const float4*>(xr + 4 * t4);
    acc = fmaf(eff[4 * t4 + 0], v.x, acc);
    acc = fmaf(eff[4 * t4 + 1], v.y, acc);
    acc = fmaf(eff[4 * t4 + 2], v.z, acc);
    acc = fmaf(eff[4 * t4 + 3], v.w, acc);
  }
  h[(size_t)node * HID + f] = acc;
}

// ---------------------------------------------------------------------------
// CSR-by-dst build
// ---------------------------------------------------------------------------
__global__ void deg_kernel(const int* __restrict__ ei, int* __restrict__ deg) {
  int e = blockIdx.x * 256 + threadIdx.x;
  if (e < N_EDGES) atomicAdd(&deg[ei[N_EDGES + e]], 1);
}

// ---- 3-phase multi-block exclusive scan over deg[0..N) -> row_ptr[0..N] ----
#define SCAN_B 256
#define SCAN_NB ((N_NODES + SCAN_B - 1) / SCAN_B)   // 196

__global__ void scan1_kernel(const int* __restrict__ deg, int* __restrict__ excl,
                             int* __restrict__ sums) {
  __shared__ int s[SCAN_B];
  int i = blockIdx.x * SCAN_B + threadIdx.x;
  int v = (i < N_NODES) ? deg[i] : 0;
  s[threadIdx.x] = v;
  __syncthreads();
  int val = v;
  for (int off = 1; off < SCAN_B; off <<= 1) {
    int add = (threadIdx.x >= off) ? s[threadIdx.x - off] : 0;
    __syncthreads();
    val += add;
    s[threadIdx.x] = val;
    __syncthreads();
  }
  if (i < N_NODES) excl[i] = val - v;
  if (threadIdx.x == SCAN_B - 1) sums[blockIdx.x] = val;
}

__global__ void scan2_kernel(int* __restrict__ sums) {  // exclusive in-place, 1 block
  __shared__ int s[SCAN_B];
  int v = (threadIdx.x < SCAN_NB) ? sums[threadIdx.x] : 0;
  s[threadIdx.x] = v;
  __syncthreads();
  int val = v;
  for (int off = 1; off < SCAN_B; off <<= 1) {
    int add = (threadIdx.x >= off) ? s[threadIdx.x - off] : 0;
    __syncthreads();
    val += add;
    s[threadIdx.x] = val;
    __syncthreads();
  }
  if (threadIdx.x < SCAN_NB) sums[threadIdx.x] = val - v;  // exclusive
  if (threadIdx.x == SCAN_NB - 1) sums[SCAN_NB] = val;     // grand total
}

__global__ void scan3_kernel(const int* __restrict__ excl, const int* __restrict__ sums,
                             int* __restrict__ row_ptr) {
  int i = blockIdx.x * SCAN_B + threadIdx.x;
  if (i < N_NODES) row_ptr[i] = excl[i] + sums[blockIdx.x];
  if (i == 0) row_ptr[N_NODES] = sums[SCAN_NB];
}

__global__ void dinv_kernel(const int* __restrict__ deg, float* __restrict__ dinv) {
  int i = blockIdx.x * 256 + threadIdx.x;
  if (i < N_NODES) dinv[i] = rsqrtf((float)(deg[i] + 1));  // +1 self-loop, deg>=1
}

__global__ void fill_kernel(const int* __restrict__ ei, const int* __restrict__ row_ptr,
                            int* __restrict__ fillc, const float* __restrict__ dinv,
                            int2* __restrict__ csr) {
  int e = blockIdx.x * 256 + threadIdx.x;
  if (e >= N_EDGES) return;
  int sN = ei[e], d = ei[N_EDGES + e];
  int p = atomicAdd(&fillc[d], 1);
  csr[row_ptr[d] + p] = make_int2(sN, __float_as_int(dinv[sN] * dinv[d]));
}

// ---------------------------------------------------------------------------
// f32 matmul: out[N_PAD,128] = h[N_PAD,128] @ W[128,128]
// block: 256 thr = 8 node-groups x 32 col-groups; thread: 4 nodes x 4 cols
// ---------------------------------------------------------------------------
__global__ __launch_bounds__(256) void matmul_kernel(const float* __restrict__ h,
                                                     const float* __restrict__ W,
                                                     float* __restrict__ out) {
  int t = threadIdx.x;
  int c0 = (t & 31) << 2;
  int n0 = blockIdx.x * 32 + ((t >> 5) << 2);
  float acc[4][4];
  #pragma unroll
  for (int i = 0; i < 4; ++i)
    #pragma unroll
    for (int j = 0; j < 4; ++j) acc[i][j] = 0.f;
  for (int k = 0; k < HID; k += 4) {
    float4 w0 = *(const float4*)(W + (k + 0) * HID + c0);
    float4 w1 = *(const float4*)(W + (k + 1) * HID + c0);
    float4 w2 = *(const float4*)(W + (k + 2) * HID + c0);
    float4 w3 = *(const float4*)(W + (k + 3) * HID + c0);
    #pragma unroll
    for (int i = 0; i < 4; ++i) {
      float4 hv = *(const float4*)(h + (size_t)(n0 + i) * HID + k);
      acc[i][0] = fmaf(hv.x, w0.x, acc[i][0]); acc[i][0] = fmaf(hv.y, w1.x, acc[i][0]);
      acc[i][0] = fmaf(hv.z, w2.x, acc[i][0]); acc[i][0] = fmaf(hv.w, w3.x, acc[i][0]);
      acc[i][1] = fmaf(hv.x, w0.y, acc[i][1]); acc[i][1] = fmaf(hv.y, w1.y, acc[i][1]);
      acc[i][1] = fmaf(hv.z, w2.y, acc[i][1]); acc[i][1] = fmaf(hv.w, w3.y, acc[i][1]);
      acc[i][2] = fmaf(hv.x, w0.z, acc[i][2]); acc[i][2] = fmaf(hv.y, w1.z, acc[i][2]);
      acc[i][2] = fmaf(hv.z, w2.z, acc[i][2]); acc[i][2] = fmaf(hv.w, w3.z, acc[i][2]);
      acc[i][3] = fmaf(hv.x, w0.w, acc[i][3]); acc[i][3] = fmaf(hv.y, w1.w, acc[i][3]);
      acc[i][3] = fmaf(hv.z, w2.w, acc[i][3]); acc[i][3] = fmaf(hv.w, w3.w, acc[i][3]);
    }
  }
  #pragma unroll
  for (int i = 0; i < 4; ++i) {
    float4 r;
    r.x = acc[i][0]; r.y = acc[i][1]; r.z = acc[i][2]; r.w = acc[i][3];
    *(float4*)(out + (size_t)(n0 + i) * HID + c0) = r;
  }
}

// ---------------------------------------------------------------------------
// Aggregate: one wave per node; lane holds channels [2l, 2l+1].
// out[v] = bias + dinv[v]^2 * hW[v] + sum_{e in CSR[v]} norm_e * hW[src_e]
// 2-edge unroll with dual accumulators for load-level ILP.
// ---------------------------------------------------------------------------
__global__ __launch_bounds__(256) void aggregate_kernel(
    const float* __restrict__ hW, const int2* __restrict__ csr,
    const int* __restrict__ row_ptr, const float* __restrict__ dinv,
    const float* __restrict__ bias, float* __restrict__ out, int relu) {
  int v = blockIdx.x * 4 + (threadIdx.x >> 6);
  if (v >= N_NODES) return;
  int lane = threadIdx.x & 63;
  float dv = dinv[v];
  float2 hs = ((const float2*)(hW + (size_t)v * HID))[lane];
  float ax = dv * dv * hs.x, ay = dv * dv * hs.y;
  float bx = 0.f, by = 0.f;
  int beg = row_ptr[v], end = row_ptr[v + 1];
  int e = beg;
  for (; e + 1 < end; e += 2) {
    int2 e0 = csr[e];
    int2 e1 = csr[e + 1];
    float n0 = __int_as_float(e0.y);
    float n1 = __int_as_float(e1.y);
    float2 h0 = ((const float2*)(hW + (size_t)e0.x * HID))[lane];
    float2 h1 = ((const float2*)(hW + (size_t)e1.x * HID))[lane];
    ax = fmaf(n0, h0.x, ax);
    ay = fmaf(n0, h0.y, ay);
    bx = fmaf(n1, h1.x, bx);
    by = fmaf(n1, h1.y, by);
  }
  if (e < end) {
    int2 e0 = csr[e];
    float n0 = __int_as_float(e0.y);
    float2 h0 = ((const float2*)(hW + (size_t)e0.x * HID))[lane];
    ax = fmaf(n0, h0.x, ax);
    ay = fmaf(n0, h0.y, ay);
  }
  ax += bx; ay += by;
  float2 b2 = ((const float2*)bias)[lane];
  ax += b2.x; ay += b2.y;
  if (relu) { ax = fmaxf(ax, 0.f); ay = fmaxf(ay, 0.f); }
  ((float2*)(out + (size_t)v * HID))[lane] = make_float2(ax, ay);
}

// ---------------------------------------------------------------------------
// Global mean pool — segmented (batch is SORTED): one block per 128-node
// chunk, 128 threads = 1 channel each; register accumulate per graph segment,
// one atomic per (segment x channel). ~100K atomics vs 6.4M naive.
// ---------------------------------------------------------------------------
#define POOL_NPB 128
__global__ __launch_bounds__(128) void pool_kernel(const float* __restrict__ h,
                                                   const int* __restrict__ batch,
                                                   float* __restrict__ pooled,
                                                   float* __restrict__ cnt) {
  int c = threadIdx.x;               // 0..127
  int n0 = blockIdx.x * POOL_NPB;
  int n1 = min(n0 + POOL_NPB, N_NODES);
  int g = batch[n0];
  float acc = 0.f;
  int segc = 0;
  for (int v = n0; v < n1; ++v) {
    int gv = batch[v];
    if (gv != g) {
      atomicAdd(&pooled[g * HID + c], acc);
      if (c == 0) atomicAdd(&cnt[g], (float)segc);
      acc = 0.f; segc = 0; g = gv;
    }
    acc += h[(size_t)v * HID + c];
    ++segc;
  }
  atomicAdd(&pooled[g * HID + c], acc);
  if (c == 0) atomicAdd(&cnt[g], (float)segc);
}

__global__ void mlp_kernel(const float* __restrict__ pooled, const float* __restrict__ cnt,
                           const float* __restrict__ l1w, const float* __restrict__ l1b,
                           const float* __restrict__ l2w, const float* __restrict__ l2b,
                           float* __restrict__ out) {
  int g = blockIdx.x, j = threadIdx.x;  // 64 threads
  float inv = 1.f / fmaxf(cnt[g], 1.f);
  float acc = l1b[j];
  #pragma unroll 8
  for (int k = 0; k < HID; ++k)
    acc = fmaf(pooled[g * HID + k] * inv, l1w[k * 64 + j], acc);
  float p = fmaxf(acc, 0.f) * l2w[j];
  #pragma unroll
  for (int off = 32; off > 0; off >>= 1) p += __shfl_down(p, off, 64);
  if (j == 0) out[g] = 1.f / (1.f + __expf(-(p + l2b[0])));
}

// ---------------------------------------------------------------------------
extern "C" void kernel_launch(void* const* d_in, const int* in_sizes, int n_in,
                              void* d_out, int out_size, void* d_ws, size_t ws_size,
                              hipStream_t stream) {
  const float* x      = (const float*)d_in[0];
  const int*   ei     = (const int*)d_in[1];
  const int*   batch  = (const int*)d_in[2];
  const float* conv_w = (const float*)d_in[3];
  const float* conv_b = (const float*)d_in[4];
  const float* W1 = (const float*)d_in[5];
  const float* b1 = (const float*)d_in[6];
  const float* W2 = (const float*)d_in[7];
  const float* b2 = (const float*)d_in[8];
  const float* W3 = (const float*)d_in[9];
  const float* b3 = (const float*)d_in[10];
  const float* l1w = (const float*)d_in[11];
  const float* l1b = (const float*)d_in[12];
  const float* l2w = (const float*)d_in[13];
  const float* l2b = (const float*)d_in[14];
  float* out = (float*)d_out;

  char* ws = (char*)d_ws;
  size_t off = 0;
  auto alloc = [&](size_t bytes) {
    void* p = ws + off;
    off = (off + bytes + 255) & ~(size_t)255;
    return p;
  };
  float* hA      = (float*)alloc((size_t)N_PAD * HID * 4);
  float* hB      = (float*)alloc((size_t)N_PAD * HID * 4);
  int*   deg     = (int*)alloc((size_t)N_NODES * 4);
  int*   row_ptr = (int*)alloc((size_t)(N_NODES + 1) * 4);
  int*   fillc   = (int*)alloc((size_t)N_NODES * 4);
  float* dinv    = (float*)alloc((size_t)N_NODES * 4);
  int2*  csr     = (int2*)alloc((size_t)N_EDGES * 8);
  float* eff     = (float*)alloc(128 * 4);
  float* pooled  = (float*)alloc((size_t)N_GRAPHS * HID * 4);
  float* cnt     = (float*)alloc((size_t)N_GRAPHS * 4);
  int*   excl    = (int*)alloc((size_t)N_NODES * 4);
  int*   sums    = (int*)alloc((size_t)(SCAN_NB + 1) * 4);

  hipMemsetAsync(deg, 0, (size_t)N_NODES * 4, stream);
  hipMemsetAsync(fillc, 0, (size_t)N_NODES * 4, stream);
  hipMemsetAsync(pooled, 0, (size_t)N_GRAPHS * HID * 4, stream);
  hipMemsetAsync(cnt, 0, (size_t)N_GRAPHS * 4, stream);

  eff_kernel<<<1, 64, 0, stream>>>(conv_w, conv_b, eff);
  conv_kernel<<<N_NODES / 2, 256, 0, stream>>>(x, eff, hA);

  deg_kernel<<<(N_EDGES + 255) / 256, 256, 0, stream>>>(ei, deg);
  scan1_kernel<<<SCAN_NB, SCAN_B, 0, stream>>>(deg, excl, sums);
  scan2_kernel<<<1, SCAN_B, 0, stream>>>(sums);
  scan3_kernel<<<SCAN_NB, SCAN_B, 0, stream>>>(excl, sums, row_ptr);
  dinv_kernel<<<(N_NODES + 255) / 256, 256, 0, stream>>>(deg, dinv);
  fill_kernel<<<(N_EDGES + 255) / 256, 256, 0, stream>>>(ei, row_ptr, fillc, dinv, csr);

  // layer 1
  matmul_kernel<<<N_PAD / 32, 256, 0, stream>>>(hA, W1, hB);
  aggregate_kernel<<<N_NODES / 4, 256, 0, stream>>>(hB, csr, row_ptr, dinv, b1, hA, 1);
  // layer 2
  matmul_kernel<<<N_PAD / 32, 256, 0, stream>>>(hA, W2, hB);
  aggregate_kernel<<<N_NODES / 4, 256, 0, stream>>>(hB, csr, row_ptr, dinv, b2, hA, 1);
  // layer 3
  matmul_kernel<<<N_PAD / 32, 256, 0, stream>>>(hA, W3, hB);
  aggregate_kernel<<<N_NODES / 4, 256, 0, stream>>>(hB, csr, row_ptr, dinv, b3, hA, 0);

  pool_kernel<<<(N_NODES + POOL_NPB - 1) / POOL_NPB, POOL_NPB, 0, stream>>>(hA, batch, pooled, cnt);
  mlp_kernel<<<N_GRAPHS, 64, 0, stream>>>(pooled, cnt, l1w, l1b, l2w, l2b, out);
}

// Round 3
// 994.275 us; speedup vs baseline: 1.4019x; 1.0687x over previous
//
#include <hip/hip_runtime.h>

#define N_NODES 50000
#define N_PAD   50016      // padded to /32 for unguarded matmul tiles
#define N_EDGES 1600000
#define N_GRAPHS 256
#define F_IN 1080
#define HID 128

typedef unsigned short u16;
typedef unsigned int u32;

// --- bf16 helpers (RNE pack, bit-op unpack) --------------------------------
static __device__ __forceinline__ u32 rne(float f) {
  u32 u = __float_as_uint(f);
  return (u + 0x7fffu + ((u >> 16) & 1u)) >> 16;
}
static __device__ __forceinline__ u32 pack2(float lo, float hi) {
  return rne(lo) | (rne(hi) << 16);
}
static __device__ __forceinline__ float bl(u32 u) { return __uint_as_float(u << 16); }
static __device__ __forceinline__ float bh(u32 u) { return __uint_as_float(u & 0xffff0000u); }

// ---------------------------------------------------------------------------
// Conv: three composed (k=10,s=2) shared-filter convs == one (k=64,s=8) conv.
// eff[t] = sum_{a+2b+4c==t} w[a]w[b]w[c]; bias b_eff = b*(s^2+s+1), s=sum(w).
// eff recomputed per block in LDS (free: kernel is HBM-bound). bf16 output.
// ---------------------------------------------------------------------------
__global__ __launch_bounds__(256) void conv_kernel(const float* __restrict__ x,
                                                   const float* __restrict__ w,
                                                   const float* __restrict__ b,
                                                   u16* __restrict__ h) {
  __shared__ float effs[65];
  if (threadIdx.x < 64) {
    int t = threadIdx.x;
    float acc = 0.f;
    for (int a = 0; a < 10; ++a)
      for (int bb = 0; bb < 10; ++bb) {
        int r = t - a - 2 * bb;
        if (r >= 0 && (r & 3) == 0 && (r >> 2) < 10)
          acc += w[a] * w[bb] * w[r >> 2];
      }
    effs[t] = acc;
    if (t == 0) {
      float s = 0.f;
      for (int i = 0; i < 10; ++i) s += w[i];
      effs[64] = b[0] * (s * s + s + 1.f);
    }
  }
  __syncthreads();
  int node = blockIdx.x * 2 + (threadIdx.x >> 7);
  int f = threadIdx.x & 127;
  if (node >= N_NODES) {                 // pad rows -> zeros (keep matmul finite)
    if (node < N_PAD) h[(size_t)node * HID + f] = 0;
    return;
  }
  const float* xr = x + (size_t)node * F_IN + 8 * f;
  float acc = effs[64];
  #pragma unroll
  for (int t4 = 0; t4 < 16; ++t4) {
    float4 v = *reinterpret_cast<const float4*>(xr + 4 * t4);
    acc = fmaf(effs[4 * t4 + 0], v.x, acc);
    acc = fmaf(effs[4 * t4 + 1], v.y, acc);
    acc = fmaf(effs[4 * t4 + 2], v.z, acc);
    acc = fmaf(effs[4 * t4 + 3], v.w, acc);
  }
  h[(size_t)node * HID + f] = (u16)rne(acc);
}

// ---------------------------------------------------------------------------
// CSR-by-dst build
// ---------------------------------------------------------------------------
__global__ void deg_kernel(const int* __restrict__ ei, int* __restrict__ deg) {
  int e = blockIdx.x * 256 + threadIdx.x;
  if (e < N_EDGES) atomicAdd(&deg[ei[N_EDGES + e]], 1);
}

#define SCAN_B 256
#define SCAN_NB ((N_NODES + SCAN_B - 1) / SCAN_B)   // 196

__global__ void scan1_kernel(const int* __restrict__ deg, int* __restrict__ excl,
                             int* __restrict__ sums, float* __restrict__ dinv) {
  __shared__ int s[SCAN_B];
  int i = blockIdx.x * SCAN_B + threadIdx.x;
  int v = (i < N_NODES) ? deg[i] : 0;
  if (i < N_NODES) dinv[i] = rsqrtf((float)(v + 1));  // +1 self-loop
  s[threadIdx.x] = v;
  __syncthreads();
  int val = v;
  for (int off = 1; off < SCAN_B; off <<= 1) {
    int add = (threadIdx.x >= off) ? s[threadIdx.x - off] : 0;
    __syncthreads();
    val += add;
    s[threadIdx.x] = val;
    __syncthreads();
  }
  if (i < N_NODES) excl[i] = val - v;
  if (threadIdx.x == SCAN_B - 1) sums[blockIdx.x] = val;
}

__global__ void scan2_kernel(int* __restrict__ sums) {  // exclusive in-place, 1 block
  __shared__ int s[SCAN_B];
  int v = (threadIdx.x < SCAN_NB) ? sums[threadIdx.x] : 0;
  s[threadIdx.x] = v;
  __syncthreads();
  int val = v;
  for (int off = 1; off < SCAN_B; off <<= 1) {
    int add = (threadIdx.x >= off) ? s[threadIdx.x - off] : 0;
    __syncthreads();
    val += add;
    s[threadIdx.x] = val;
    __syncthreads();
  }
  if (threadIdx.x < SCAN_NB) sums[threadIdx.x] = val - v;
  if (threadIdx.x == SCAN_NB - 1) sums[SCAN_NB] = val;
}

__global__ void scan3_kernel(const int* __restrict__ excl, const int* __restrict__ sums,
                             int* __restrict__ row_ptr) {
  int i = blockIdx.x * SCAN_B + threadIdx.x;
  if (i < N_NODES) row_ptr[i] = excl[i] + sums[blockIdx.x];
  if (i == 0) row_ptr[N_NODES] = sums[SCAN_NB];
}

__global__ void fill_kernel(const int* __restrict__ ei, const int* __restrict__ row_ptr,
                            int* __restrict__ fillc, const float* __restrict__ dinv,
                            int2* __restrict__ csr) {
  int e = blockIdx.x * 256 + threadIdx.x;
  if (e >= N_EDGES) return;
  int sN = ei[e], d = ei[N_EDGES + e];
  int p = atomicAdd(&fillc[d], 1);
  csr[row_ptr[d] + p] = make_int2(sN, __float_as_int(dinv[sN] * dinv[d]));
}

// ---------------------------------------------------------------------------
// matmul: out[N_PAD,128](bf16) = h[N_PAD,128](bf16) @ W[128,128](f32), f32 acc
// block: 256 thr = 8 node-groups x 32 col-groups; thread: 4 nodes x 4 cols
// ---------------------------------------------------------------------------
__global__ __launch_bounds__(256) void matmul_kernel(const u16* __restrict__ h,
                                                     const float* __restrict__ W,
                                                     u16* __restrict__ out) {
  int t = threadIdx.x;
  int c0 = (t & 31) << 2;
  int n0 = blockIdx.x * 32 + ((t >> 5) << 2);
  float acc[4][4];
  #pragma unroll
  for (int i = 0; i < 4; ++i)
    #pragma unroll
    for (int j = 0; j < 4; ++j) acc[i][j] = 0.f;
  for (int k = 0; k < HID; k += 4) {
    float4 w0 = *(const float4*)(W + (k + 0) * HID + c0);
    float4 w1 = *(const float4*)(W + (k + 1) * HID + c0);
    float4 w2 = *(const float4*)(W + (k + 2) * HID + c0);
    float4 w3 = *(const float4*)(W + (k + 3) * HID + c0);
    #pragma unroll
    for (int i = 0; i < 4; ++i) {
      uint2 hu = *(const uint2*)(h + (size_t)(n0 + i) * HID + k);
      float f0 = bl(hu.x), f1 = bh(hu.x), f2 = bl(hu.y), f3 = bh(hu.y);
      acc[i][0] = fmaf(f0, w0.x, acc[i][0]); acc[i][0] = fmaf(f1, w1.x, acc[i][0]);
      acc[i][0] = fmaf(f2, w2.x, acc[i][0]); acc[i][0] = fmaf(f3, w3.x, acc[i][0]);
      acc[i][1] = fmaf(f0, w0.y, acc[i][1]); acc[i][1] = fmaf(f1, w1.y, acc[i][1]);
      acc[i][1] = fmaf(f2, w2.y, acc[i][1]); acc[i][1] = fmaf(f3, w3.y, acc[i][1]);
      acc[i][2] = fmaf(f0, w0.z, acc[i][2]); acc[i][2] = fmaf(f1, w1.z, acc[i][2]);
      acc[i][2] = fmaf(f2, w2.z, acc[i][2]); acc[i][2] = fmaf(f3, w3.z, acc[i][2]);
      acc[i][3] = fmaf(f0, w0.w, acc[i][3]); acc[i][3] = fmaf(f1, w1.w, acc[i][3]);
      acc[i][3] = fmaf(f2, w2.w, acc[i][3]); acc[i][3] = fmaf(f3, w3.w, acc[i][3]);
    }
  }
  #pragma unroll
  for (int i = 0; i < 4; ++i) {
    uint2 o;
    o.x = pack2(acc[i][0], acc[i][1]);
    o.y = pack2(acc[i][2], acc[i][3]);
    *(uint2*)(out + (size_t)(n0 + i) * HID + c0) = o;
  }
}

// ---------------------------------------------------------------------------
// Aggregate: one wave per node; half-wave per edge (2 edges in parallel).
// lane = 32*half + li; li covers 4 channels c0=4*li via one uint2 (256B/row).
// out[v] = bias + dinv[v]^2*hW[v] + sum_e norm_e*hW[src_e]; f32 acc, bf16 i/o.
// ---------------------------------------------------------------------------
__global__ __launch_bounds__(256) void aggregate_kernel(
    const u16* __restrict__ hW, const int2* __restrict__ csr,
    const int* __restrict__ row_ptr, const float* __restrict__ dinv,
    const float* __restrict__ bias, u16* __restrict__ out, int relu) {
  int v = blockIdx.x * 4 + (threadIdx.x >> 6);
  if (v >= N_NODES) return;
  int lane = threadIdx.x & 63;
  int half = lane >> 5, li = lane & 31;
  float dv = dinv[v];
  float sw = (half == 0) ? dv * dv : 0.f;
  uint2 sv = ((const uint2*)(hW + (size_t)v * HID))[li];
  float a0 = sw * bl(sv.x), a1 = sw * bh(sv.x), a2 = sw * bl(sv.y), a3 = sw * bh(sv.y);
  float b0 = 0.f, b1 = 0.f, b2 = 0.f, b3 = 0.f;
  int beg = row_ptr[v], end = row_ptr[v + 1];
  int e = beg + half;
  for (; e + 2 < end; e += 4) {          // 2 edges per half-wave in flight
    int2 e0 = csr[e];
    int2 e1 = csr[e + 2];
    uint2 g0 = ((const uint2*)(hW + (size_t)e0.x * HID))[li];
    uint2 g1 = ((const uint2*)(hW + (size_t)e1.x * HID))[li];
    float n0 = __int_as_float(e0.y), n1 = __int_as_float(e1.y);
    a0 = fmaf(n0, bl(g0.x), a0); a1 = fmaf(n0, bh(g0.x), a1);
    a2 = fmaf(n0, bl(g0.y), a2); a3 = fmaf(n0, bh(g0.y), a3);
    b0 = fmaf(n1, bl(g1.x), b0); b1 = fmaf(n1, bh(g1.x), b1);
    b2 = fmaf(n1, bl(g1.y), b2); b3 = fmaf(n1, bh(g1.y), b3);
  }
  if (e < end) {
    int2 e0 = csr[e];
    uint2 g0 = ((const uint2*)(hW + (size_t)e0.x * HID))[li];
    float n0 = __int_as_float(e0.y);
    a0 = fmaf(n0, bl(g0.x), a0); a1 = fmaf(n0, bh(g0.x), a1);
    a2 = fmaf(n0, bl(g0.y), a2); a3 = fmaf(n0, bh(g0.y), a3);
  }
  a0 += b0; a1 += b1; a2 += b2; a3 += b3;
  a0 += __shfl_xor(a0, 32); a1 += __shfl_xor(a1, 32);
  a2 += __shfl_xor(a2, 32); a3 += __shfl_xor(a3, 32);
  if (half == 0) {
    float4 bv = *(const float4*)(bias + 4 * li);
    a0 += bv.x; a1 += bv.y; a2 += bv.z; a3 += bv.w;
    if (relu) {
      a0 = fmaxf(a0, 0.f); a1 = fmaxf(a1, 0.f);
      a2 = fmaxf(a2, 0.f); a3 = fmaxf(a3, 0.f);
    }
    uint2 o; o.x = pack2(a0, a1); o.y = pack2(a2, a3);
    ((uint2*)(out + (size_t)v * HID))[li] = o;
  }
}

// ---------------------------------------------------------------------------
// Global mean pool — segmented (batch is SORTED); bf16 in, f32 atomic out.
// ---------------------------------------------------------------------------
#define POOL_NPB 128
__global__ __launch_bounds__(128) void pool_kernel(const u16* __restrict__ h,
                                                   const int* __restrict__ batch,
                                                   float* __restrict__ pooled,
                                                   float* __restrict__ cnt) {
  int c = threadIdx.x;
  int n0 = blockIdx.x * POOL_NPB;
  int n1 = min(n0 + POOL_NPB, N_NODES);
  int g = batch[n0];
  float acc = 0.f;
  int segc = 0;
  for (int v = n0; v < n1; ++v) {
    int gv = batch[v];
    if (gv != g) {
      atomicAdd(&pooled[g * HID + c], acc);
      if (c == 0) atomicAdd(&cnt[g], (float)segc);
      acc = 0.f; segc = 0; g = gv;
    }
    acc += bl((u32)h[(size_t)v * HID + c]);
    ++segc;
  }
  atomicAdd(&pooled[g * HID + c], acc);
  if (c == 0) atomicAdd(&cnt[g], (float)segc);
}

__global__ void mlp_kernel(const float* __restrict__ pooled, const float* __restrict__ cnt,
                           const float* __restrict__ l1w, const float* __restrict__ l1b,
                           const float* __restrict__ l2w, const float* __restrict__ l2b,
                           float* __restrict__ out) {
  int g = blockIdx.x, j = threadIdx.x;  // 64 threads
  float inv = 1.f / fmaxf(cnt[g], 1.f);
  float acc = l1b[j];
  #pragma unroll 8
  for (int k = 0; k < HID; ++k)
    acc = fmaf(pooled[g * HID + k] * inv, l1w[k * 64 + j], acc);
  float p = fmaxf(acc, 0.f) * l2w[j];
  #pragma unroll
  for (int off = 32; off > 0; off >>= 1) p += __shfl_down(p, off, 64);
  if (j == 0) out[g] = 1.f / (1.f + __expf(-(p + l2b[0])));
}

// ---------------------------------------------------------------------------
extern "C" void kernel_launch(void* const* d_in, const int* in_sizes, int n_in,
                              void* d_out, int out_size, void* d_ws, size_t ws_size,
                              hipStream_t stream) {
  const float* x      = (const float*)d_in[0];
  const int*   ei     = (const int*)d_in[1];
  const int*   batch  = (const int*)d_in[2];
  const float* conv_w = (const float*)d_in[3];
  const float* conv_b = (const float*)d_in[4];
  const float* W1 = (const float*)d_in[5];
  const float* b1 = (const float*)d_in[6];
  const float* W2 = (const float*)d_in[7];
  const float* b2 = (const float*)d_in[8];
  const float* W3 = (const float*)d_in[9];
  const float* b3 = (const float*)d_in[10];
  const float* l1w = (const float*)d_in[11];
  const float* l1b = (const float*)d_in[12];
  const float* l2w = (const float*)d_in[13];
  const float* l2b = (const float*)d_in[14];
  float* out = (float*)d_out;

  char* ws = (char*)d_ws;
  size_t off = 0;
  auto alloc = [&](size_t bytes) {
    void* p = ws + off;
    off = (off + bytes + 255) & ~(size_t)255;
    return p;
  };
  u16*   B0      = (u16*)alloc((size_t)N_PAD * HID * 2);   // conv out / agg out
  u16*   B1      = (u16*)alloc((size_t)N_PAD * HID * 2);   // matmul out
  int*   deg     = (int*)alloc((size_t)N_NODES * 4);
  int*   row_ptr = (int*)alloc((size_t)(N_NODES + 1) * 4);
  int*   fillc   = (int*)alloc((size_t)N_NODES * 4);
  float* dinv    = (float*)alloc((size_t)N_NODES * 4);
  int2*  csr     = (int2*)alloc((size_t)N_EDGES * 8);
  float* pooled  = (float*)alloc((size_t)N_GRAPHS * HID * 4);
  float* cnt     = (float*)alloc((size_t)N_GRAPHS * 4);
  int*   excl    = (int*)alloc((size_t)N_NODES * 4);
  int*   sums    = (int*)alloc((size_t)(SCAN_NB + 1) * 4);

  hipMemsetAsync(deg, 0, (size_t)N_NODES * 4, stream);
  hipMemsetAsync(fillc, 0, (size_t)N_NODES * 4, stream);
  hipMemsetAsync(pooled, 0, (size_t)N_GRAPHS * HID * 4, stream);
  hipMemsetAsync(cnt, 0, (size_t)N_GRAPHS * 4, stream);

  conv_kernel<<<N_PAD / 2, 256, 0, stream>>>(x, conv_w, conv_b, B0);

  deg_kernel<<<(N_EDGES + 255) / 256, 256, 0, stream>>>(ei, deg);
  scan1_kernel<<<SCAN_NB, SCAN_B, 0, stream>>>(deg, excl, sums, dinv);
  scan2_kernel<<<1, SCAN_B, 0, stream>>>(sums);
  scan3_kernel<<<SCAN_NB, SCAN_B, 0, stream>>>(excl, sums, row_ptr);
  fill_kernel<<<(N_EDGES + 255) / 256, 256, 0, stream>>>(ei, row_ptr, fillc, dinv, csr);

  // layer 1
  matmul_kernel<<<N_PAD / 32, 256, 0, stream>>>(B0, W1, B1);
  aggregate_kernel<<<N_NODES / 4, 256, 0, stream>>>(B1, csr, row_ptr, dinv, b1, B0, 1);
  // layer 2
  matmul_kernel<<<N_PAD / 32, 256, 0, stream>>>(B0, W2, B1);
  aggregate_kernel<<<N_NODES / 4, 256, 0, stream>>>(B1, csr, row_ptr, dinv, b2, B0, 1);
  // layer 3
  matmul_kernel<<<N_PAD / 32, 256, 0, stream>>>(B0, W3, B1);
  aggregate_kernel<<<N_NODES / 4, 256, 0, stream>>>(B1, csr, row_ptr, dinv, b3, B0, 0);

  pool_kernel<<<(N_NODES + POOL_NPB - 1) / POOL_NPB, POOL_NPB, 0, stream>>>(B0, batch, pooled, cnt);
  mlp_kernel<<<N_GRAPHS, 64, 0, stream>>>(pooled, cnt, l1w, l1b, l2w, l2b, out);
}